// Round 4
// baseline (102406.958 us; speedup 1.0000x reference)
//
#include <hip/hip_runtime.h>

// Sparse 3D UNet forward (fp32). Round 4: W via double-buffered LDS chunks
// (broadcast ds_read_b128), G via per-lane register pipeline, idx prefetch
// distance 2. lane = output row, acc[COUT/4] float4.
// EPI: 0 = relu(y*s+b); 1 = +skip; 2 = relu(...) + pair-reduce(cat).

template<int CIN_A, int CIN_B, int COUT, int EPI, bool SPLIT>
__global__ __launch_bounds__(256, (COUT == 32 ? 4 : 3)) void spconv(
    const float* __restrict__ inA,
    const float* __restrict__ inB,
    const int*   __restrict__ nbr,   // [N][27]
    const float* __restrict__ W,     // [27][CIN][COUT]
    const float* __restrict__ bn,    // [2][COUT]
    const float* __restrict__ skip,  // EPI==1 residual
    float*       __restrict__ out,   // [N][COUT] (non-split)
    float*       __restrict__ pout,  // [KS][N][COUT] partials (split)
    int N, int KS)
{
    constexpr int  CIN   = CIN_A + CIN_B;
    constexpr int  NQ    = COUT / 4;
    constexpr bool WHOLE = (CIN < 32);            // CIN=4 first conv
    constexpr int  CH    = WHOLE ? CIN : 32;      // ci per chunk
    constexpr int  NCH   = CIN / CH;              // 1,2,4
    constexpr int  CHV   = CH / 4;                // float4 of G per chunk
    constexpr int  CHW   = CH * COUT;             // floats of W per chunk
    constexpr int  WPT   = (CHW / 4 + 255) / 256; // staged float4/thread
    constexpr int  LOG_NCH = (NCH == 1 ? 0 : (NCH == 2 ? 1 : 2));

    __shared__ float s_w[WHOLE ? 27 * CHW : 2 * CHW];

    const int tid = threadIdx.x;

    // bijective XCD-aware swizzle (m204)
    unsigned nwg = gridDim.x;
    unsigned q8 = nwg / 8u, r8 = nwg % 8u;
    unsigned xcd = blockIdx.x % 8u, sub = blockIdx.x / 8u;
    unsigned id = (xcd < r8 ? xcd * (q8 + 1u) : r8 * (q8 + 1u) + (xcd - r8) * q8) + sub;

    int kg, rb;
    if (SPLIT) { kg = (int)(id % (unsigned)KS); rb = (int)(id / (unsigned)KS); }
    else       { kg = 0;  rb = (int)id; }
    const int kper = SPLIT ? 27 / KS : 27;
    const int k0 = kg * kper, k1 = k0 + kper;

    const int  row = rb * 256 + tid;
    const bool rv  = row < N;
    const int* nbrp = nbr + (size_t)row * 27;

    float4 acc[NQ];
    #pragma unroll
    for (int q = 0; q < NQ; ++q) acc[q] = make_float4(0.f, 0.f, 0.f, 0.f);

    int   idxT1, idxT2;
    float mkA, mkB;

    if constexpr (WHOLE) {
        // ---- stage all taps' W once ----
        const int totv = kper * CHW / 4;
        const float4* wp = (const float4*)(W + (size_t)k0 * CHW);
        for (int e = tid; e < totv; e += 256) ((float4*)s_w)[e] = wp[e];

        idxT1 = rv ? nbrp[k0] : -1;
        { int kn = (k0 + 1 > k1 - 1) ? k1 - 1 : k0 + 1; idxT2 = rv ? nbrp[kn] : -1; }
        mkA = (idxT1 >= 0) ? 1.f : 0.f;
        float4 gA = *(const float4*)(inA + (size_t)((idxT1 >= 0) ? idxT1 : 0) * CIN_A);
        float4 gB;
        __syncthreads();

        for (int k = k0; k < k1; ++k) {
            // issue G(k+1), idx distance-2
            if (k + 1 < k1) {
                idxT1 = idxT2;
                int kn = (k + 2 > k1 - 1) ? k1 - 1 : k + 2;
                idxT2 = rv ? nbrp[kn] : -1;
            }
            mkB = (idxT1 >= 0) ? 1.f : 0.f;
            gB = *(const float4*)(inA + (size_t)((idxT1 >= 0) ? idxT1 : 0) * CIN_A);
            // FMA tap k
            const float* bw = s_w + (size_t)(k - k0) * CHW;
            #pragma unroll
            for (int j = 0; j < 4; ++j) {
                const float gv = (&gA.x)[j] * mkA;
                const float4* wr = (const float4*)(bw + j * COUT);
                #pragma unroll
                for (int q = 0; q < NQ; ++q) {
                    float4 w = wr[q];
                    acc[q].x += gv * w.x; acc[q].y += gv * w.y;
                    acc[q].z += gv * w.z; acc[q].w += gv * w.w;
                }
            }
            gA = gB; mkA = mkB;
        }
    } else {
        const int S = kper * NCH;
        float4 gA[CHV], gB[CHV];
        float4 wA[WPT], wB[WPT];

        // ---- prologue ----
        { // W_0 -> wB -> buf0
            const float4* wp = (const float4*)(W + (size_t)k0 * CIN * COUT);
            #pragma unroll
            for (int j = 0; j < WPT; ++j) wB[j] = wp[tid + j * 256];
            #pragma unroll
            for (int j = 0; j < WPT; ++j) ((float4*)s_w)[tid + j * 256] = wB[j];
        }
        { // W_1 -> wA (clamped)
            int s2 = (S > 1) ? 1 : 0;
            const float4* wp = (const float4*)(W + ((size_t)(k0 + (s2 >> LOG_NCH)) * CIN
                                 + (size_t)(s2 & (NCH - 1)) * CH) * COUT);
            #pragma unroll
            for (int j = 0; j < WPT; ++j) wA[j] = wp[tid + j * 256];
        }
        idxT1 = rv ? nbrp[k0] : -1;
        { int kn = (k0 + 1 > k1 - 1) ? k1 - 1 : k0 + 1; idxT2 = rv ? nbrp[kn] : -1; }
        mkA = (idxT1 >= 0) ? 1.f : 0.f;
        { // G_0 (chunk 0 is always inA)
            const float* rp = inA + (size_t)((idxT1 >= 0) ? idxT1 : 0) * CIN_A;
            #pragma unroll
            for (int v = 0; v < CHV; ++v) gA[v] = ((const float4*)rp)[v];
        }
        __syncthreads();

#define STEP(sv, WC, WN, GC, GN, MKC, MKN)                                          \
        {                                                                           \
            const int p_ = (sv) & 1;                                                \
            float* dst_ = s_w + (p_ ^ 1) * CHW;                                     \
            _Pragma("unroll")                                                       \
            for (int j_ = 0; j_ < WPT; ++j_)                                        \
                ((float4*)dst_)[tid + j_ * 256] = WC[j_];                           \
            { int s2_ = (sv) + 2; if (s2_ > S - 1) s2_ = S - 1;                     \
              const float4* wp_ = (const float4*)(W +                               \
                  ((size_t)(k0 + (s2_ >> LOG_NCH)) * CIN                            \
                   + (size_t)(s2_ & (NCH - 1)) * CH) * COUT);                       \
              _Pragma("unroll")                                                     \
              for (int j_ = 0; j_ < WPT; ++j_) WN[j_] = wp_[tid + j_ * 256]; }      \
            { int t_ = (sv) + 1; if (t_ > S - 1) t_ = S - 1;                        \
              int ct_ = t_ & (NCH - 1);                                             \
              if (ct_ == 0 && t_ == (sv) + 1) {                                     \
                  idxT1 = idxT2;                                                    \
                  int kn_ = k0 + (t_ >> LOG_NCH) + 1;                               \
                  if (kn_ > k1 - 1) kn_ = k1 - 1;                                   \
                  idxT2 = rv ? nbrp[kn_] : -1;                                      \
              }                                                                     \
              MKN = (idxT1 >= 0) ? 1.f : 0.f;                                       \
              const int si_ = (idxT1 >= 0) ? idxT1 : 0;                             \
              const int cb_ = ct_ * CH;                                             \
              const float* rp_ = (CIN_B == 0 || cb_ < CIN_A)                        \
                  ? inA + (size_t)si_ * CIN_A + cb_                                 \
                  : inB + (size_t)si_ * CIN_B + (cb_ - CIN_A);                      \
              _Pragma("unroll")                                                     \
              for (int v_ = 0; v_ < CHV; ++v_) GN[v_] = ((const float4*)rp_)[v_]; } \
            { const float* bw_ = s_w + p_ * CHW;                                    \
              _Pragma("unroll")                                                     \
              for (int cq_ = 0; cq_ < CHV; ++cq_) {                                 \
                  _Pragma("unroll")                                                 \
                  for (int j_ = 0; j_ < 4; ++j_) {                                  \
                      const float gv_ = (&GC[cq_].x)[j_] * MKC;                     \
                      const float4* wr_ = (const float4*)(bw_ + (cq_ * 4 + j_) * COUT); \
                      _Pragma("unroll")                                             \
                      for (int q_ = 0; q_ < NQ; ++q_) {                             \
                          float4 w_ = wr_[q_];                                      \
                          acc[q_].x += gv_ * w_.x; acc[q_].y += gv_ * w_.y;         \
                          acc[q_].z += gv_ * w_.z; acc[q_].w += gv_ * w_.w;         \
                      }                                                             \
                  }                                                                 \
              }                                                                     \
            }                                                                       \
            __syncthreads();                                                        \
        }

        int s = 0;
        while (s + 2 <= S) {
            STEP(s,     wA, wB, gA, gB, mkA, mkB);
            STEP(s + 1, wB, wA, gB, gA, mkB, mkA);
            s += 2;
        }
        if (s < S) STEP(s, wA, wB, gA, gB, mkA, mkB);
#undef STEP
    }

    // ---- epilogue ----
    const int co0 = 0;
    (void)co0;
    if (SPLIT) {
        if (rv) {
            float* pp = pout + ((size_t)kg * N + row) * COUT;
            #pragma unroll
            for (int q = 0; q < NQ; ++q) *(float4*)(pp + q * 4) = acc[q];
        }
        return;
    }
    if (!rv) return;

    float*       op   = out + (size_t)row * COUT;
    const float* skp  = (EPI == 1) ? skip + (size_t)row * COUT : nullptr;
    const float* catA = inA + (size_t)row * CIN_A;
    const float* catB = (CIN_B > 0) ? inB + (size_t)row * CIN_B : nullptr;

    #pragma unroll
    for (int q = 0; q < NQ; ++q) {
        float4 sc = *(const float4*)(bn + q * 4);
        float4 bi = *(const float4*)(bn + COUT + q * 4);
        float4 y;
        y.x = acc[q].x * sc.x + bi.x;
        y.y = acc[q].y * sc.y + bi.y;
        y.z = acc[q].z * sc.z + bi.z;
        y.w = acc[q].w * sc.w + bi.w;
        if (EPI == 1) {
            float4 s = *(const float4*)(skp + q * 4);
            y.x += s.x; y.y += s.y; y.z += s.z; y.w += s.w;
        }
        y.x = fmaxf(y.x, 0.f); y.y = fmaxf(y.y, 0.f);
        y.z = fmaxf(y.z, 0.f); y.w = fmaxf(y.w, 0.f);
        if (EPI == 2) {
            const float* rs = (8 * q < CIN_A) ? catA + 8 * q : catB + 8 * q - CIN_A;
            float4 p0 = ((const float4*)rs)[0];
            float4 p1 = ((const float4*)rs)[1];
            y.x += p0.x + p0.y; y.y += p0.z + p0.w;
            y.z += p1.x + p1.y; y.w += p1.z + p1.w;
        }
        *(float4*)(op + q * 4) = y;
    }
}

// Sum split-K partials + BN/ReLU/skip/pair-reduce epilogue.
template<int CIN_A, int CIN_B, int COUT, int EPI>
__global__ __launch_bounds__(256) void epi_k(
    const float* __restrict__ P, int KS,
    const float* __restrict__ bn,
    const float* __restrict__ skip,
    const float* __restrict__ inA,
    const float* __restrict__ inB,
    float* __restrict__ out, int N)
{
    int t = blockIdx.x * 256 + threadIdx.x;
    int total = N * (COUT / 4);
    if (t >= total) return;
    int r   = t / (COUT / 4);
    int co0 = (t % (COUT / 4)) * 4;

    float4 y = make_float4(0.f, 0.f, 0.f, 0.f);
    for (int kg = 0; kg < KS; ++kg) {
        float4 p = *(const float4*)(P + ((size_t)kg * N + r) * COUT + co0);
        y.x += p.x; y.y += p.y; y.z += p.z; y.w += p.w;
    }
    float4 sc = *(const float4*)(bn + co0);
    float4 bi = *(const float4*)(bn + COUT + co0);
    y.x = y.x * sc.x + bi.x; y.y = y.y * sc.y + bi.y;
    y.z = y.z * sc.z + bi.z; y.w = y.w * sc.w + bi.w;
    if (EPI == 1) {
        float4 s = *(const float4*)(skip + (size_t)r * COUT + co0);
        y.x += s.x; y.y += s.y; y.z += s.z; y.w += s.w;
    }
    y.x = fmaxf(y.x, 0.f); y.y = fmaxf(y.y, 0.f);
    y.z = fmaxf(y.z, 0.f); y.w = fmaxf(y.w, 0.f);
    if (EPI == 2) {
        const float* rs = (2 * co0 < CIN_A)
            ? inA + (size_t)r * CIN_A + 2 * co0
            : inB + (size_t)r * CIN_B + 2 * co0 - CIN_A;
        float4 p0 = ((const float4*)rs)[0];
        float4 p1 = ((const float4*)rs)[1];
        y.x += p0.x + p0.y; y.y += p0.z + p0.w;
        y.z += p1.x + p1.y; y.w += p1.z + p1.w;
    }
    *(float4*)(out + (size_t)r * COUT + co0) = y;
}

// smallest KS in {1,3,9,27} giving >=768 blocks, clamped to ws budget
static inline int ksel(int nblk, int N, int CO, size_t prem_elems) {
    int ks = 27;
    if (nblk >= 768) ks = 1;
    else if (nblk * 3 >= 768) ks = 3;
    else if (nblk * 9 >= 768) ks = 9;
    while (ks > 1 && (size_t)ks * (size_t)N * (size_t)CO > prem_elems) ks /= 3;
    return ks;
}

extern "C" void kernel_launch(void* const* d_in, const int* in_sizes, int n_in,
                              void* d_out, int out_size, void* d_ws, size_t ws_size,
                              hipStream_t stream)
{
    (void)n_in; (void)out_size;
    const float* vf     = (const float*)d_in[0];
    const float* Win    = (const float*)d_in[1];
    const float* W32    = (const float*)d_in[2];
    const float* W64    = (const float*)d_in[3];
    const float* Wd3    = (const float*)d_in[4];
    const float* W6432  = (const float*)d_in[5];
    const float* W12864 = (const float*)d_in[6];
    const float* bn32   = (const float*)d_in[7];
    const float* bn64   = (const float*)d_in[8];
    const int* nbr1  = (const int*)d_in[9];
    const int* nbr2  = (const int*)d_in[10];
    const int* nbr3  = (const int*)d_in[11];
    const int* nbr4  = (const int*)d_in[12];
    const int* nbrd2 = (const int*)d_in[13];
    const int* nbrd3 = (const int*)d_in[14];
    const int* nbrd4 = (const int*)d_in[15];
    const int* nbri4 = (const int*)d_in[16];
    const int* nbri3 = (const int*)d_in[17];
    const int* nbri2 = (const int*)d_in[18];

    const int N1 = in_sizes[9]  / 27;
    const int N2 = in_sizes[10] / 27;
    const int N3 = in_sizes[11] / 27;
    const int N4 = in_sizes[12] / 27;

    float* ws = (float*)d_ws;
    size_t off = 0;
    auto alloc = [&](size_t n) { float* p = ws + off; off += n; return p; };
    float* X1  = alloc((size_t)N1 * 32);
    float* TA  = alloc((size_t)N1 * 32);
    float* TA2 = alloc((size_t)N1 * 32);
    float* TU1 = alloc((size_t)N1 * 32);
    float* X2  = alloc((size_t)N2 * 32);
    float* TB2 = alloc((size_t)N2 * 32);
    float* TC2 = alloc((size_t)N2 * 32);
    float* TU2 = alloc((size_t)N2 * 32);
    float* X3  = alloc((size_t)N3 * 64);
    float* TB3 = alloc((size_t)N3 * 64);
    float* TC3 = alloc((size_t)N3 * 64);
    float* TU3 = alloc((size_t)N3 * 64);
    float* X4  = alloc((size_t)N4 * 64);
    float* TB4 = alloc((size_t)N4 * 64);
    float* TC4 = alloc((size_t)N4 * 64);
    float* OUT = (float*)d_out;

    size_t prem = (ws_size / 4 > off + 1024) ? (ws_size / 4 - off - 1024) : 0;
    float* P = ws + off;

    const size_t S32 = 27*32*32, S64 = (size_t)27*64*64, S6432 = (size_t)27*64*32, S12864 = (size_t)27*128*64;

#define CONV(CA, CB, CO, EP, pA, pB, pN, pW, pBN, pS, pO, NN) do {                      \
        int nblk_ = ((NN) + 255) / 256;                                                 \
        int ks_ = ksel(nblk_, (NN), (CO), prem);                                        \
        if (ks_ == 1) {                                                                 \
            spconv<CA, CB, CO, EP, false><<<dim3((unsigned)nblk_), 256, 0, stream>>>(   \
                pA, pB, pN, pW, pBN, pS, pO, nullptr, NN, 1);                           \
        } else {                                                                        \
            spconv<CA, CB, CO, EP, true><<<dim3((unsigned)(nblk_ * ks_)), 256, 0, stream>>>( \
                pA, pB, pN, pW, pBN, pS, nullptr, P, NN, ks_);                          \
            int tot4_ = (NN) * ((CO) / 4);                                              \
            epi_k<CA, CB, CO, EP><<<dim3((unsigned)((tot4_ + 255) / 256)), 256, 0, stream>>>( \
                P, ks_, pBN, pS, pA, pB, pO, NN);                                       \
        }                                                                               \
    } while (0)

    // ---------------- encoder ----------------
    CONV(4,0,32,0,  vf,  nullptr, nbr1,  Win,         bn32+0*64,  nullptr, TA,  N1);
    CONV(32,0,32,0, TA,  nullptr, nbr1,  W32+0*S32,   bn32+1*64,  nullptr, X1,  N1);
    CONV(32,0,32,0, X1,  nullptr, nbrd2, W32+1*S32,   bn32+2*64,  nullptr, TB2, N2);
    CONV(32,0,32,0, TB2, nullptr, nbr2,  W32+2*S32,   bn32+3*64,  nullptr, TC2, N2);
    CONV(32,0,32,0, TC2, nullptr, nbr2,  W32+3*S32,   bn32+4*64,  nullptr, X2,  N2);
    CONV(32,0,64,0, X2,  nullptr, nbrd3, Wd3,         bn64+0*128, nullptr, TB3, N3);
    CONV(64,0,64,0, TB3, nullptr, nbr3,  W64+0*S64,   bn64+1*128, nullptr, TC3, N3);
    CONV(64,0,64,0, TC3, nullptr, nbr3,  W64+1*S64,   bn64+2*128, nullptr, X3,  N3);
    CONV(64,0,64,0, X3,  nullptr, nbrd4, W64+2*S64,   bn64+3*128, nullptr, TB4, N4);
    CONV(64,0,64,0, TB4, nullptr, nbr4,  W64+3*S64,   bn64+4*128, nullptr, TC4, N4);
    CONV(64,0,64,0, TC4, nullptr, nbr4,  W64+4*S64,   bn64+5*128, nullptr, X4,  N4);
    // ---------------- bottleneck ----------------
    CONV(64,0,64,0, X4,  nullptr, nbr4,  W64+5*S64,   bn64+6*128, nullptr, TB4, N4);
    CONV(64,0,64,1, TB4, nullptr, nbr4,  W64+6*S64,   bn64+7*128, X4,      TC4, N4);
    CONV(64,64,64,2, X4, TC4,     nbr4,  W12864+0*S12864, bn64+11*128, nullptr, TB4, N4);
    // ---------------- decoder: 4 -> 3 ----------------
    CONV(64,0,64,0, TB4, nullptr, nbri4, W64+7*S64,   bn64+8*128, nullptr, TU3, N3);
    CONV(64,0,64,0, X3,  nullptr, nbr3,  W64+8*S64,   bn64+9*128, nullptr, TB3, N3);
    CONV(64,0,64,1, TB3, nullptr, nbr3,  W64+9*S64,   bn64+10*128, X3,     TC3, N3);
    CONV(64,64,64,2, TU3, TC3,    nbr3,  W12864+1*S12864, bn64+12*128, nullptr, TB3, N3);
    // ---------------- decoder: 3 -> 2 ----------------
    CONV(64,0,32,0, TB3, nullptr, nbri3, W6432+0*S6432, bn32+11*64, nullptr, TU2, N2);
    CONV(32,0,32,0, X2,  nullptr, nbr2,  W32+4*S32,   bn32+5*64,  nullptr, TB2, N2);
    CONV(32,0,32,1, TB2, nullptr, nbr2,  W32+5*S32,   bn32+6*64,  X2,      TC2, N2);
    CONV(32,32,32,2, TU2, TC2,    nbr2,  W6432+1*S6432, bn32+12*64, nullptr, TB2, N2);
    // ---------------- decoder: 2 -> 1 ----------------
    CONV(32,0,32,0, TB2, nullptr, nbri2, W32+6*S32,   bn32+7*64,  nullptr, TU1, N1);
    CONV(32,0,32,0, X1,  nullptr, nbr1,  W32+7*S32,   bn32+8*64,  nullptr, TA,  N1);
    CONV(32,0,32,1, TA,  nullptr, nbr1,  W32+8*S32,   bn32+9*64,  X1,      TA2, N1);
    CONV(32,32,32,2, TU1, TA2,    nbr1,  W6432+2*S6432, bn32+13*64, nullptr, TA,  N1);
    // ---------------- head ----------------
    CONV(32,0,32,0, TA,  nullptr, nbr1,  W32+9*S32,   bn32+10*64, nullptr, OUT, N1);
#undef CONV
}

// Round 5
// 4437.868 us; speedup vs baseline: 23.0757x; 23.0757x over previous
//
#include <hip/hip_runtime.h>

// Sparse 3D UNet forward (fp32). Round 5: SGPR-weight implicit GEMM.
// lane = output row; acc[COUT] floats in VGPRs; W rows pulled through the
// scalar pipe (s_load_dwordx16 -> SGPRs) and consumed directly as the SGPR
// operand of v_fmac -- no LDS, no barriers, no per-lane W loads.
// Wave-level __ballot skip of all-invalid taps (big win on nbri convs).
// EPI: 0 = relu(y*s+b); 1 = +skip; 2 = relu(...) + pair-reduce(cat).

typedef float f32x16 __attribute__((ext_vector_type(16)));

template<int CIN_A, int CIN_B, int COUT, int EPI, bool SPLIT>
__global__ __launch_bounds__(256) void spconv(
    const float* __restrict__ inA,
    const float* __restrict__ inB,
    const int*   __restrict__ nbr,   // [N][27]
    const float* __restrict__ W,     // [27][CIN][COUT]
    const float* __restrict__ bn,    // [2][COUT]
    const float* __restrict__ skip,  // EPI==1 residual
    float*       __restrict__ out,   // [N][COUT] (non-split)
    float*       __restrict__ pout,  // [KS][N][COUT] partials (split)
    int N, int KS)
{
    constexpr int CIN   = CIN_A + CIN_B;
    constexpr int CHUNK = (CIN >= 32) ? 32 : CIN;   // ci per G register chunk
    constexpr int NCHK  = CIN / CHUNK;
    constexpr int GV    = CHUNK / 4;                // float4 of G per chunk
    constexpr int NSTEP = CHUNK * COUT / 64;        // 64 W floats per step

    const int tid = threadIdx.x;

    // bijective XCD-aware swizzle (m204)
    unsigned nwg = gridDim.x;
    unsigned q8 = nwg / 8u, r8 = nwg % 8u;
    unsigned xcd = blockIdx.x % 8u, sub = blockIdx.x / 8u;
    unsigned id = (xcd < r8 ? xcd * (q8 + 1u) : r8 * (q8 + 1u) + (xcd - r8) * q8) + sub;

    int kg, rb;
    if (SPLIT) { kg = (int)(id % (unsigned)KS); rb = (int)(id / (unsigned)KS); }
    else       { kg = 0;  rb = (int)id; }
    const int kper = SPLIT ? 27 / KS : 27;
    const int k0 = kg * kper, k1 = k0 + kper;

    const int  row = rb * 256 + tid;
    const bool rv  = row < N;
    const int* nbrp = nbr + (size_t)row * 27;

    float acc[COUT];
    #pragma unroll
    for (int i = 0; i < COUT; ++i) acc[i] = 0.f;

    int idx = rv ? nbrp[k0] : -1;
    for (int k = k0; k < k1; ++k) {
        const int nidx = (rv && k + 1 < k1) ? nbrp[k + 1] : -1;  // prefetch
        if (__ballot(idx >= 0) != 0ull) {
            const float mk = (idx >= 0) ? 1.f : 0.f;
            const int   si = (idx >= 0) ? idx : 0;
            const float* wk = W + (size_t)k * (CIN * COUT);

            #pragma unroll 1
            for (int c = 0; c < NCHK; ++c) {
                // ---- G chunk: per-lane float4 global loads ----
                const float* src;
                if constexpr (CIN_B == 0)
                    src = inA + (size_t)si * CIN_A + c * CHUNK;
                else
                    src = (c * CHUNK < CIN_A)
                        ? inA + (size_t)si * CIN_A + c * CHUNK
                        : inB + (size_t)si * CIN_B + (c * CHUNK - CIN_A);
                float4 g[GV];
                #pragma unroll
                for (int v = 0; v < GV; ++v) g[v] = ((const float4*)src)[v];
                #pragma unroll
                for (int v = 0; v < GV; ++v) {
                    g[v].x *= mk; g[v].y *= mk; g[v].z *= mk; g[v].w *= mk;
                }

                const float* wkc = wk + c * (CHUNK * COUT);
                // ---- steps of 64 W floats (1 ci @COUT=64, 2 ci @COUT=32) ----
                #pragma unroll
                for (int ss = 0; ss < NSTEP; ++ss) {
                    const float* wp = wkc + ss * 64;
                    f32x16 w0, w1, w2, w3;
                    asm volatile("s_load_dwordx16 %0, %1, 0x0"  : "=s"(w0) : "s"(wp));
                    asm volatile("s_load_dwordx16 %0, %1, 0x40" : "=s"(w1) : "s"(wp));
                    asm volatile("s_load_dwordx16 %0, %1, 0x80" : "=s"(w2) : "s"(wp));
                    asm volatile("s_load_dwordx16 %0, %1, 0xc0" : "=s"(w3) : "s"(wp));
                    asm volatile("s_waitcnt lgkmcnt(0)"
                                 : "+s"(w0), "+s"(w1), "+s"(w2), "+s"(w3));
                    if constexpr (COUT == 64) {
                        const int ci = ss;
                        const float gv = ((const float*)&g[ci >> 2])[ci & 3];
                        #pragma unroll
                        for (int q = 0; q < 16; ++q) acc[q]      += gv * w0[q];
                        #pragma unroll
                        for (int q = 0; q < 16; ++q) acc[16 + q] += gv * w1[q];
                        #pragma unroll
                        for (int q = 0; q < 16; ++q) acc[32 + q] += gv * w2[q];
                        #pragma unroll
                        for (int q = 0; q < 16; ++q) acc[48 + q] += gv * w3[q];
                    } else {  // COUT == 32: two ci per step
                        const int ci0 = 2 * ss, ci1 = 2 * ss + 1;
                        const float gv0 = ((const float*)&g[ci0 >> 2])[ci0 & 3];
                        const float gv1 = ((const float*)&g[ci1 >> 2])[ci1 & 3];
                        #pragma unroll
                        for (int q = 0; q < 16; ++q) acc[q]      += gv0 * w0[q];
                        #pragma unroll
                        for (int q = 0; q < 16; ++q) acc[16 + q] += gv0 * w1[q];
                        #pragma unroll
                        for (int q = 0; q < 16; ++q) acc[q]      += gv1 * w2[q];
                        #pragma unroll
                        for (int q = 0; q < 16; ++q) acc[16 + q] += gv1 * w3[q];
                    }
                }
            }
        }
        idx = nidx;
    }

    if (SPLIT) {
        if (rv) {
            float* pp = pout + ((size_t)kg * N + row) * COUT;
            #pragma unroll
            for (int q = 0; q < COUT / 4; ++q)
                *(float4*)(pp + q * 4) = make_float4(acc[4*q], acc[4*q+1], acc[4*q+2], acc[4*q+3]);
        }
        return;
    }
    if (!rv) return;

    float*       op   = out + (size_t)row * COUT;
    const float* skp  = (EPI == 1) ? skip + (size_t)row * COUT : nullptr;
    const float* catA = inA + (size_t)row * CIN_A;
    const float* catB = (CIN_B > 0) ? inB + (size_t)row * CIN_B : nullptr;

    #pragma unroll
    for (int q = 0; q < COUT / 4; ++q) {
        float4 sc = *(const float4*)(bn + q * 4);
        float4 bi = *(const float4*)(bn + COUT + q * 4);
        float4 y;
        y.x = acc[4*q+0] * sc.x + bi.x;
        y.y = acc[4*q+1] * sc.y + bi.y;
        y.z = acc[4*q+2] * sc.z + bi.z;
        y.w = acc[4*q+3] * sc.w + bi.w;
        if (EPI == 1) {
            float4 s = *(const float4*)(skp + q * 4);
            y.x += s.x; y.y += s.y; y.z += s.z; y.w += s.w;
        }
        y.x = fmaxf(y.x, 0.f); y.y = fmaxf(y.y, 0.f);
        y.z = fmaxf(y.z, 0.f); y.w = fmaxf(y.w, 0.f);
        if (EPI == 2) {
            const float* rs = (8 * q < CIN_A) ? catA + 8 * q : catB + 8 * q - CIN_A;
            float4 p0 = ((const float4*)rs)[0];
            float4 p1 = ((const float4*)rs)[1];
            y.x += p0.x + p0.y; y.y += p0.z + p0.w;
            y.z += p1.x + p1.y; y.w += p1.z + p1.w;
        }
        *(float4*)(op + q * 4) = y;
    }
}

// Sum split-K partials + BN/ReLU/skip/pair-reduce epilogue.
template<int CIN_A, int CIN_B, int COUT, int EPI>
__global__ __launch_bounds__(256) void epi_k(
    const float* __restrict__ P, int KS,
    const float* __restrict__ bn,
    const float* __restrict__ skip,
    const float* __restrict__ inA,
    const float* __restrict__ inB,
    float* __restrict__ out, int N)
{
    int t = blockIdx.x * 256 + threadIdx.x;
    int total = N * (COUT / 4);
    if (t >= total) return;
    int r   = t / (COUT / 4);
    int co0 = (t % (COUT / 4)) * 4;

    float4 y = make_float4(0.f, 0.f, 0.f, 0.f);
    for (int kg = 0; kg < KS; ++kg) {
        float4 p = *(const float4*)(P + ((size_t)kg * N + r) * COUT + co0);
        y.x += p.x; y.y += p.y; y.z += p.z; y.w += p.w;
    }
    float4 sc = *(const float4*)(bn + co0);
    float4 bi = *(const float4*)(bn + COUT + co0);
    y.x = y.x * sc.x + bi.x; y.y = y.y * sc.y + bi.y;
    y.z = y.z * sc.z + bi.z; y.w = y.w * sc.w + bi.w;
    if (EPI == 1) {
        float4 s = *(const float4*)(skip + (size_t)r * COUT + co0);
        y.x += s.x; y.y += s.y; y.z += s.z; y.w += s.w;
    }
    y.x = fmaxf(y.x, 0.f); y.y = fmaxf(y.y, 0.f);
    y.z = fmaxf(y.z, 0.f); y.w = fmaxf(y.w, 0.f);
    if (EPI == 2) {
        const float* rs = (2 * co0 < CIN_A)
            ? inA + (size_t)r * CIN_A + 2 * co0
            : inB + (size_t)r * CIN_B + 2 * co0 - CIN_A;
        float4 p0 = ((const float4*)rs)[0];
        float4 p1 = ((const float4*)rs)[1];
        y.x += p0.x + p0.y; y.y += p0.z + p0.w;
        y.z += p1.x + p1.y; y.w += p1.z + p1.w;
    }
    *(float4*)(out + (size_t)r * COUT + co0) = y;
}

// smallest KS in {1,3,9,27} giving >=640 blocks, clamped to ws budget
static inline int ksel(int nblk, int N, int CO, size_t prem_elems) {
    int ks = 27;
    if (nblk >= 640) ks = 1;
    else if (nblk * 3 >= 640) ks = 3;
    else if (nblk * 9 >= 640) ks = 9;
    while (ks > 1 && (size_t)ks * (size_t)N * (size_t)CO > prem_elems) ks /= 3;
    return ks;
}

extern "C" void kernel_launch(void* const* d_in, const int* in_sizes, int n_in,
                              void* d_out, int out_size, void* d_ws, size_t ws_size,
                              hipStream_t stream)
{
    (void)n_in; (void)out_size;
    const float* vf     = (const float*)d_in[0];
    const float* Win    = (const float*)d_in[1];
    const float* W32    = (const float*)d_in[2];
    const float* W64    = (const float*)d_in[3];
    const float* Wd3    = (const float*)d_in[4];
    const float* W6432  = (const float*)d_in[5];
    const float* W12864 = (const float*)d_in[6];
    const float* bn32   = (const float*)d_in[7];
    const float* bn64   = (const float*)d_in[8];
    const int* nbr1  = (const int*)d_in[9];
    const int* nbr2  = (const int*)d_in[10];
    const int* nbr3  = (const int*)d_in[11];
    const int* nbr4  = (const int*)d_in[12];
    const int* nbrd2 = (const int*)d_in[13];
    const int* nbrd3 = (const int*)d_in[14];
    const int* nbrd4 = (const int*)d_in[15];
    const int* nbri4 = (const int*)d_in[16];
    const int* nbri3 = (const int*)d_in[17];
    const int* nbri2 = (const int*)d_in[18];

    const int N1 = in_sizes[9]  / 27;
    const int N2 = in_sizes[10] / 27;
    const int N3 = in_sizes[11] / 27;
    const int N4 = in_sizes[12] / 27;

    float* ws = (float*)d_ws;
    size_t off = 0;
    auto alloc = [&](size_t n) { float* p = ws + off; off += n; return p; };
    float* X1  = alloc((size_t)N1 * 32);
    float* TA  = alloc((size_t)N1 * 32);
    float* TA2 = alloc((size_t)N1 * 32);
    float* TU1 = alloc((size_t)N1 * 32);
    float* X2  = alloc((size_t)N2 * 32);
    float* TB2 = alloc((size_t)N2 * 32);
    float* TC2 = alloc((size_t)N2 * 32);
    float* TU2 = alloc((size_t)N2 * 32);
    float* X3  = alloc((size_t)N3 * 64);
    float* TB3 = alloc((size_t)N3 * 64);
    float* TC3 = alloc((size_t)N3 * 64);
    float* TU3 = alloc((size_t)N3 * 64);
    float* X4  = alloc((size_t)N4 * 64);
    float* TB4 = alloc((size_t)N4 * 64);
    float* TC4 = alloc((size_t)N4 * 64);
    float* OUT = (float*)d_out;

    size_t prem = (ws_size / 4 > off + 1024) ? (ws_size / 4 - off - 1024) : 0;
    float* P = ws + off;

    const size_t S32 = 27*32*32, S64 = (size_t)27*64*64, S6432 = (size_t)27*64*32, S12864 = (size_t)27*128*64;

#define CONV(CA, CB, CO, EP, pA, pB, pN, pW, pBN, pS, pO, NN) do {                      \
        int nblk_ = ((NN) + 255) / 256;                                                 \
        int ks_ = ksel(nblk_, (NN), (CO), prem);                                        \
        if (ks_ == 1) {                                                                 \
            spconv<CA, CB, CO, EP, false><<<dim3((unsigned)nblk_), 256, 0, stream>>>(   \
                pA, pB, pN, pW, pBN, pS, pO, nullptr, NN, 1);                           \
        } else {                                                                        \
            spconv<CA, CB, CO, EP, true><<<dim3((unsigned)(nblk_ * ks_)), 256, 0, stream>>>( \
                pA, pB, pN, pW, pBN, pS, nullptr, P, NN, ks_);                          \
            int tot4_ = (NN) * ((CO) / 4);                                              \
            epi_k<CA, CB, CO, EP><<<dim3((unsigned)((tot4_ + 255) / 256)), 256, 0, stream>>>( \
                P, ks_, pBN, pS, pA, pB, pO, NN);                                       \
        }                                                                               \
    } while (0)

    // ---------------- encoder ----------------
    CONV(4,0,32,0,  vf,  nullptr, nbr1,  Win,         bn32+0*64,  nullptr, TA,  N1);
    CONV(32,0,32,0, TA,  nullptr, nbr1,  W32+0*S32,   bn32+1*64,  nullptr, X1,  N1);
    CONV(32,0,32,0, X1,  nullptr, nbrd2, W32+1*S32,   bn32+2*64,  nullptr, TB2, N2);
    CONV(32,0,32,0, TB2, nullptr, nbr2,  W32+2*S32,   bn32+3*64,  nullptr, TC2, N2);
    CONV(32,0,32,0, TC2, nullptr, nbr2,  W32+3*S32,   bn32+4*64,  nullptr, X2,  N2);
    CONV(32,0,64,0, X2,  nullptr, nbrd3, Wd3,         bn64+0*128, nullptr, TB3, N3);
    CONV(64,0,64,0, TB3, nullptr, nbr3,  W64+0*S64,   bn64+1*128, nullptr, TC3, N3);
    CONV(64,0,64,0, TC3, nullptr, nbr3,  W64+1*S64,   bn64+2*128, nullptr, X3,  N3);
    CONV(64,0,64,0, X3,  nullptr, nbrd4, W64+2*S64,   bn64+3*128, nullptr, TB4, N4);
    CONV(64,0,64,0, TB4, nullptr, nbr4,  W64+3*S64,   bn64+4*128, nullptr, TC4, N4);
    CONV(64,0,64,0, TC4, nullptr, nbr4,  W64+4*S64,   bn64+5*128, nullptr, X4,  N4);
    // ---------------- bottleneck ----------------
    CONV(64,0,64,0, X4,  nullptr, nbr4,  W64+5*S64,   bn64+6*128, nullptr, TB4, N4);
    CONV(64,0,64,1, TB4, nullptr, nbr4,  W64+6*S64,   bn64+7*128, X4,      TC4, N4);
    CONV(64,64,64,2, X4, TC4,     nbr4,  W12864+0*S12864, bn64+11*128, nullptr, TB4, N4);
    // ---------------- decoder: 4 -> 3 ----------------
    CONV(64,0,64,0, TB4, nullptr, nbri4, W64+7*S64,   bn64+8*128, nullptr, TU3, N3);
    CONV(64,0,64,0, X3,  nullptr, nbr3,  W64+8*S64,   bn64+9*128, nullptr, TB3, N3);
    CONV(64,0,64,1, TB3, nullptr, nbr3,  W64+9*S64,   bn64+10*128, X3,     TC3, N3);
    CONV(64,64,64,2, TU3, TC3,    nbr3,  W12864+1*S12864, bn64+12*128, nullptr, TB3, N3);
    // ---------------- decoder: 3 -> 2 ----------------
    CONV(64,0,32,0, TB3, nullptr, nbri3, W6432+0*S6432, bn32+11*64, nullptr, TU2, N2);
    CONV(32,0,32,0, X2,  nullptr, nbr2,  W32+4*S32,   bn32+5*64,  nullptr, TB2, N2);
    CONV(32,0,32,1, TB2, nullptr, nbr2,  W32+5*S32,   bn32+6*64,  X2,      TC2, N2);
    CONV(32,32,32,2, TU2, TC2,    nbr2,  W6432+1*S6432, bn32+12*64, nullptr, TB2, N2);
    // ---------------- decoder: 2 -> 1 ----------------
    CONV(32,0,32,0, TB2, nullptr, nbri2, W32+6*S32,   bn32+7*64,  nullptr, TU1, N1);
    CONV(32,0,32,0, X1,  nullptr, nbr1,  W32+7*S32,   bn32+8*64,  nullptr, TA,  N1);
    CONV(32,0,32,1, TA,  nullptr, nbr1,  W32+8*S32,   bn32+9*64,  X1,      TA2, N1);
    CONV(32,32,32,2, TU1, TA2,    nbr1,  W6432+2*S6432, bn32+13*64, nullptr, TA,  N1);
    // ---------------- head ----------------
    CONV(32,0,32,0, TA,  nullptr, nbr1,  W32+9*S32,   bn32+10*64, nullptr, OUT, N1);
#undef CONV
}

// Round 7
// 4198.363 us; speedup vs baseline: 24.3921x; 1.0570x over previous
//
#include <hip/hip_runtime.h>

// Sparse 3D UNet forward (fp32). Round 7: channel-split waves (R6 fixed).
// Block = 64 rows x 4 waves; wave w computes output channels
// [w*COUT/4,(w+1)*COUT/4) for all 64 rows -> 4x wave concurrency with zero
// partial traffic. wid hoisted to SGPR via readfirstlane so W addresses are
// provably uniform (s_load_dwordx16/8 -> SGPR operand of v_fmac).
// G is per-lane float4 gathers (L1-shared across the 4 waves).
// No LDS, no barriers. Grid split-K only when blocks < 1024.
// EPI: 0 = relu(y*s+b); 1 = +skip; 2 = relu(...) + pair-reduce(cat).

typedef float f32x16 __attribute__((ext_vector_type(16)));
typedef float f32x8  __attribute__((ext_vector_type(8)));

template<int CIN_A, int CIN_B, int COUT, int EPI, bool SPLIT>
__global__ __launch_bounds__(256) void spconv(
    const float* __restrict__ inA,
    const float* __restrict__ inB,
    const int*   __restrict__ nbr,   // [N][27]
    const float* __restrict__ W,     // [27][CIN][COUT]
    const float* __restrict__ bn,    // [2][COUT]
    const float* __restrict__ skip,  // EPI==1 residual
    float*       __restrict__ out,   // [N][COUT] (non-split)
    float*       __restrict__ pout,  // [KS][N][COUT] partials (split)
    int N, int KS)
{
    constexpr int CIN   = CIN_A + CIN_B;
    constexpr int CPW   = COUT / 4;              // channels per wave: 16 or 8
    constexpr int CHUNK = (CIN >= 32) ? 32 : CIN;
    constexpr int NCHK  = CIN / CHUNK;
    constexpr int GV    = CHUNK / 4;             // float4 of G per chunk
    constexpr int NB4   = CHUNK / 4;             // 4-ci batches per chunk

    const int tid  = threadIdx.x;
    const int lane = tid & 63;
    // wave id is wave-uniform; readfirstlane makes it PROVABLY uniform (SGPR)
    const int wid  = __builtin_amdgcn_readfirstlane(tid >> 6);
    const int co0  = wid * CPW;

    // bijective XCD-aware swizzle (m204)
    unsigned nwg = gridDim.x;
    unsigned q8 = nwg / 8u, r8 = nwg % 8u;
    unsigned xcd = blockIdx.x % 8u, sub = blockIdx.x / 8u;
    unsigned id = (xcd < r8 ? xcd * (q8 + 1u) : r8 * (q8 + 1u) + (xcd - r8) * q8) + sub;

    int kg, rb;
    if (SPLIT) { kg = (int)(id % (unsigned)KS); rb = (int)(id / (unsigned)KS); }
    else       { kg = 0;  rb = (int)id; }
    const int kper = SPLIT ? 27 / KS : 27;
    const int k0 = kg * kper, k1 = k0 + kper;

    const int  row = rb * 64 + lane;
    const bool rv  = row < N;
    const int* nbrp = nbr + (size_t)row * 27;

    float acc[CPW];
    #pragma unroll
    for (int i = 0; i < CPW; ++i) acc[i] = 0.f;

    int idx = rv ? nbrp[k0] : -1;
    for (int k = k0; k < k1; ++k) {
        const int nidx = (rv && k + 1 < k1) ? nbrp[k + 1] : -1;  // prefetch
        if (__ballot(idx >= 0) != 0ull) {
            const float mk = (idx >= 0) ? 1.f : 0.f;
            const int   si = (idx >= 0) ? idx : 0;
            const float* wkb = W + (size_t)k * (CIN * COUT) + co0;

            #pragma unroll
            for (int c = 0; c < NCHK; ++c) {
                // ---- G chunk: per-lane float4 gathers (shared via L1) ----
                const float* src;
                if constexpr (CIN_B == 0)
                    src = inA + (size_t)si * CIN_A + c * CHUNK;
                else
                    src = (c * CHUNK < CIN_A)
                        ? inA + (size_t)si * CIN_A + c * CHUNK
                        : inB + (size_t)si * CIN_B + (c * CHUNK - CIN_A);
                float4 g[GV];
                #pragma unroll
                for (int v = 0; v < GV; ++v) g[v] = ((const float4*)src)[v];
                #pragma unroll
                for (int v = 0; v < GV; ++v) {
                    g[v].x *= mk; g[v].y *= mk; g[v].z *= mk; g[v].w *= mk;
                }

                const float* wp0 = wkb + (size_t)(c * CHUNK) * COUT;
                // ---- 4-ci batches: 4 scalar loads, one wait, 4*CPW FMAs ----
                #pragma unroll
                for (int b = 0; b < NB4; ++b) {
                    const float* wp = wp0 + (size_t)(4 * b) * COUT;
                    const float g0 = (&g[b].x)[0];
                    const float g1 = (&g[b].x)[1];
                    const float g2 = (&g[b].x)[2];
                    const float g3 = (&g[b].x)[3];
                    if constexpr (COUT == 64) {
                        f32x16 w0, w1, w2, w3;
                        asm volatile("s_load_dwordx16 %0, %1, 0x0"   : "=s"(w0) : "s"(wp));
                        asm volatile("s_load_dwordx16 %0, %1, 0x100" : "=s"(w1) : "s"(wp));
                        asm volatile("s_load_dwordx16 %0, %1, 0x200" : "=s"(w2) : "s"(wp));
                        asm volatile("s_load_dwordx16 %0, %1, 0x300" : "=s"(w3) : "s"(wp));
                        asm volatile("s_waitcnt lgkmcnt(0)"
                                     : "+s"(w0), "+s"(w1), "+s"(w2), "+s"(w3));
                        #pragma unroll
                        for (int q = 0; q < 16; ++q) acc[q] += g0 * w0[q];
                        #pragma unroll
                        for (int q = 0; q < 16; ++q) acc[q] += g1 * w1[q];
                        #pragma unroll
                        for (int q = 0; q < 16; ++q) acc[q] += g2 * w2[q];
                        #pragma unroll
                        for (int q = 0; q < 16; ++q) acc[q] += g3 * w3[q];
                    } else {  // COUT == 32
                        f32x8 w0, w1, w2, w3;
                        asm volatile("s_load_dwordx8 %0, %1, 0x0"   : "=s"(w0) : "s"(wp));
                        asm volatile("s_load_dwordx8 %0, %1, 0x80"  : "=s"(w1) : "s"(wp));
                        asm volatile("s_load_dwordx8 %0, %1, 0x100" : "=s"(w2) : "s"(wp));
                        asm volatile("s_load_dwordx8 %0, %1, 0x180" : "=s"(w3) : "s"(wp));
                        asm volatile("s_waitcnt lgkmcnt(0)"
                                     : "+s"(w0), "+s"(w1), "+s"(w2), "+s"(w3));
                        #pragma unroll
                        for (int q = 0; q < 8; ++q) acc[q] += g0 * w0[q];
                        #pragma unroll
                        for (int q = 0; q < 8; ++q) acc[q] += g1 * w1[q];
                        #pragma unroll
                        for (int q = 0; q < 8; ++q) acc[q] += g2 * w2[q];
                        #pragma unroll
                        for (int q = 0; q < 8; ++q) acc[q] += g3 * w3[q];
                    }
                }
            }
        }
        idx = nidx;
    }

    if (SPLIT) {
        if (rv) {
            float* pp = pout + ((size_t)kg * N + row) * COUT + co0;
            #pragma unroll
            for (int q = 0; q < CPW / 4; ++q)
                *(float4*)(pp + q * 4) =
                    make_float4(acc[4*q], acc[4*q+1], acc[4*q+2], acc[4*q+3]);
        }
        return;
    }
    if (!rv) return;

    float*       op   = out + (size_t)row * COUT + co0;
    const float* skp  = (EPI == 1) ? skip + (size_t)row * COUT + co0 : nullptr;
    const float* catA = inA + (size_t)row * CIN_A;
    const float* catB = (CIN_B > 0) ? inB + (size_t)row * CIN_B : nullptr;

    #pragma unroll
    for (int q = 0; q < CPW / 4; ++q) {
        float4 sc = *(const float4*)(bn + co0 + q * 4);
        float4 bi = *(const float4*)(bn + COUT + co0 + q * 4);
        float4 y;
        y.x = acc[4*q+0] * sc.x + bi.x;
        y.y = acc[4*q+1] * sc.y + bi.y;
        y.z = acc[4*q+2] * sc.z + bi.z;
        y.w = acc[4*q+3] * sc.w + bi.w;
        if (EPI == 1) {
            float4 s = *(const float4*)(skp + q * 4);
            y.x += s.x; y.y += s.y; y.z += s.z; y.w += s.w;
        }
        y.x = fmaxf(y.x, 0.f); y.y = fmaxf(y.y, 0.f);
        y.z = fmaxf(y.z, 0.f); y.w = fmaxf(y.w, 0.f);
        if (EPI == 2) {
            const int c2 = 2 * (co0 + 4 * q);
            const float* rs = (c2 < CIN_A) ? catA + c2 : catB + c2 - CIN_A;
            float4 p0 = ((const float4*)rs)[0];
            float4 p1 = ((const float4*)rs)[1];
            y.x += p0.x + p0.y; y.y += p0.z + p0.w;
            y.z += p1.x + p1.y; y.w += p1.z + p1.w;
        }
        *(float4*)(op + q * 4) = y;
    }
}

// Sum split-K partials + BN/ReLU/skip/pair-reduce epilogue.
template<int CIN_A, int CIN_B, int COUT, int EPI>
__global__ __launch_bounds__(256) void epi_k(
    const float* __restrict__ P, int KS,
    const float* __restrict__ bn,
    const float* __restrict__ skip,
    const float* __restrict__ inA,
    const float* __restrict__ inB,
    float* __restrict__ out, int N)
{
    int t = blockIdx.x * 256 + threadIdx.x;
    int total = N * (COUT / 4);
    if (t >= total) return;
    int r   = t / (COUT / 4);
    int co0 = (t % (COUT / 4)) * 4;

    float4 y = make_float4(0.f, 0.f, 0.f, 0.f);
    for (int kg = 0; kg < KS; ++kg) {
        float4 p = *(const float4*)(P + ((size_t)kg * N + r) * COUT + co0);
        y.x += p.x; y.y += p.y; y.z += p.z; y.w += p.w;
    }
    float4 sc = *(const float4*)(bn + co0);
    float4 bi = *(const float4*)(bn + COUT + co0);
    y.x = y.x * sc.x + bi.x; y.y = y.y * sc.y + bi.y;
    y.z = y.z * sc.z + bi.z; y.w = y.w * sc.w + bi.w;
    if (EPI == 1) {
        float4 s = *(const float4*)(skip + (size_t)r * COUT + co0);
        y.x += s.x; y.y += s.y; y.z += s.z; y.w += s.w;
    }
    y.x = fmaxf(y.x, 0.f); y.y = fmaxf(y.y, 0.f);
    y.z = fmaxf(y.z, 0.f); y.w = fmaxf(y.w, 0.f);
    if (EPI == 2) {
        const float* rs = (2 * co0 < CIN_A)
            ? inA + (size_t)r * CIN_A + 2 * co0
            : inB + (size_t)r * CIN_B + 2 * co0 - CIN_A;
        float4 p0 = ((const float4*)rs)[0];
        float4 p1 = ((const float4*)rs)[1];
        y.x += p0.x + p0.y; y.y += p0.z + p0.w;
        y.z += p1.x + p1.y; y.w += p1.z + p1.w;
    }
    *(float4*)(out + (size_t)r * COUT + co0) = y;
}

// smallest KS in {1,3,9} giving >=1024 blocks, clamped to ws budget
static inline int ksel(int nblk, int N, int CO, size_t prem_elems) {
    int ks;
    if (nblk >= 1024) ks = 1;
    else if (nblk * 3 >= 1024) ks = 3;
    else ks = 9;
    while (ks > 1 && (size_t)ks * (size_t)N * (size_t)CO > prem_elems) ks /= 3;
    return ks;
}

extern "C" void kernel_launch(void* const* d_in, const int* in_sizes, int n_in,
                              void* d_out, int out_size, void* d_ws, size_t ws_size,
                              hipStream_t stream)
{
    (void)n_in; (void)out_size;
    const float* vf     = (const float*)d_in[0];
    const float* Win    = (const float*)d_in[1];
    const float* W32    = (const float*)d_in[2];
    const float* W64    = (const float*)d_in[3];
    const float* Wd3    = (const float*)d_in[4];
    const float* W6432  = (const float*)d_in[5];
    const float* W12864 = (const float*)d_in[6];
    const float* bn32   = (const float*)d_in[7];
    const float* bn64   = (const float*)d_in[8];
    const int* nbr1  = (const int*)d_in[9];
    const int* nbr2  = (const int*)d_in[10];
    const int* nbr3  = (const int*)d_in[11];
    const int* nbr4  = (const int*)d_in[12];
    const int* nbrd2 = (const int*)d_in[13];
    const int* nbrd3 = (const int*)d_in[14];
    const int* nbrd4 = (const int*)d_in[15];
    const int* nbri4 = (const int*)d_in[16];
    const int* nbri3 = (const int*)d_in[17];
    const int* nbri2 = (const int*)d_in[18];

    const int N1 = in_sizes[9]  / 27;
    const int N2 = in_sizes[10] / 27;
    const int N3 = in_sizes[11] / 27;
    const int N4 = in_sizes[12] / 27;

    float* ws = (float*)d_ws;
    size_t off = 0;
    auto alloc = [&](size_t n) { float* p = ws + off; off += n; return p; };
    float* X1  = alloc((size_t)N1 * 32);
    float* TA  = alloc((size_t)N1 * 32);
    float* TA2 = alloc((size_t)N1 * 32);
    float* TU1 = alloc((size_t)N1 * 32);
    float* X2  = alloc((size_t)N2 * 32);
    float* TB2 = alloc((size_t)N2 * 32);
    float* TC2 = alloc((size_t)N2 * 32);
    float* TU2 = alloc((size_t)N2 * 32);
    float* X3  = alloc((size_t)N3 * 64);
    float* TB3 = alloc((size_t)N3 * 64);
    float* TC3 = alloc((size_t)N3 * 64);
    float* TU3 = alloc((size_t)N3 * 64);
    float* X4  = alloc((size_t)N4 * 64);
    float* TB4 = alloc((size_t)N4 * 64);
    float* TC4 = alloc((size_t)N4 * 64);
    float* OUT = (float*)d_out;

    size_t prem = (ws_size / 4 > off + 1024) ? (ws_size / 4 - off - 1024) : 0;
    float* P = ws + off;

    const size_t S32 = 27*32*32, S64 = (size_t)27*64*64, S6432 = (size_t)27*64*32, S12864 = (size_t)27*128*64;

#define CONV(CA, CB, CO, EP, pA, pB, pN, pW, pBN, pS, pO, NN) do {                      \
        int nblk_ = ((NN) + 63) / 64;                                                   \
        int ks_ = ksel(nblk_, (NN), (CO), prem);                                        \
        if (ks_ == 1) {                                                                 \
            spconv<CA, CB, CO, EP, false><<<dim3((unsigned)nblk_), 256, 0, stream>>>(   \
                pA, pB, pN, pW, pBN, pS, pO, nullptr, NN, 1);                           \
        } else {                                                                        \
            spconv<CA, CB, CO, EP, true><<<dim3((unsigned)(nblk_ * ks_)), 256, 0, stream>>>( \
                pA, pB, pN, pW, pBN, pS, nullptr, P, NN, ks_);                          \
            int tot4_ = (NN) * ((CO) / 4);                                              \
            epi_k<CA, CB, CO, EP><<<dim3((unsigned)((tot4_ + 255) / 256)), 256, 0, stream>>>( \
                P, ks_, pBN, pS, pA, pB, pO, NN);                                       \
        }                                                                               \
    } while (0)

    // ---------------- encoder ----------------
    CONV(4,0,32,0,  vf,  nullptr, nbr1,  Win,         bn32+0*64,  nullptr, TA,  N1);
    CONV(32,0,32,0, TA,  nullptr, nbr1,  W32+0*S32,   bn32+1*64,  nullptr, X1,  N1);
    CONV(32,0,32,0, X1,  nullptr, nbrd2, W32+1*S32,   bn32+2*64,  nullptr, TB2, N2);
    CONV(32,0,32,0, TB2, nullptr, nbr2,  W32+2*S32,   bn32+3*64,  nullptr, TC2, N2);
    CONV(32,0,32,0, TC2, nullptr, nbr2,  W32+3*S32,   bn32+4*64,  nullptr, X2,  N2);
    CONV(32,0,64,0, X2,  nullptr, nbrd3, Wd3,         bn64+0*128, nullptr, TB3, N3);
    CONV(64,0,64,0, TB3, nullptr, nbr3,  W64+0*S64,   bn64+1*128, nullptr, TC3, N3);
    CONV(64,0,64,0, TC3, nullptr, nbr3,  W64+1*S64,   bn64+2*128, nullptr, X3,  N3);
    CONV(64,0,64,0, X3,  nullptr, nbrd4, W64+2*S64,   bn64+3*128, nullptr, TB4, N4);
    CONV(64,0,64,0, TB4, nullptr, nbr4,  W64+3*S64,   bn64+4*128, nullptr, TC4, N4);
    CONV(64,0,64,0, TC4, nullptr, nbr4,  W64+4*S64,   bn64+5*128, nullptr, X4,  N4);
    // ---------------- bottleneck ----------------
    CONV(64,0,64,0, X4,  nullptr, nbr4,  W64+5*S64,   bn64+6*128, nullptr, TB4, N4);
    CONV(64,0,64,1, TB4, nullptr, nbr4,  W64+6*S64,   bn64+7*128, X4,      TC4, N4);
    CONV(64,64,64,2, X4, TC4,     nbr4,  W12864+0*S12864, bn64+11*128, nullptr, TB4, N4);
    // ---------------- decoder: 4 -> 3 ----------------
    CONV(64,0,64,0, TB4, nullptr, nbri4, W64+7*S64,   bn64+8*128, nullptr, TU3, N3);
    CONV(64,0,64,0, X3,  nullptr, nbr3,  W64+8*S64,   bn64+9*128, nullptr, TB3, N3);
    CONV(64,0,64,1, TB3, nullptr, nbr3,  W64+9*S64,   bn64+10*128, X3,     TC3, N3);
    CONV(64,64,64,2, TU3, TC3,    nbr3,  W12864+1*S12864, bn64+12*128, nullptr, TB3, N3);
    // ---------------- decoder: 3 -> 2 ----------------
    CONV(64,0,32,0, TB3, nullptr, nbri3, W6432+0*S6432, bn32+11*64, nullptr, TU2, N2);
    CONV(32,0,32,0, X2,  nullptr, nbr2,  W32+4*S32,   bn32+5*64,  nullptr, TB2, N2);
    CONV(32,0,32,1, TB2, nullptr, nbr2,  W32+5*S32,   bn32+6*64,  X2,      TC2, N2);
    CONV(32,32,32,2, TU2, TC2,    nbr2,  W6432+1*S6432, bn32+12*64, nullptr, TB2, N2);
    // ---------------- decoder: 2 -> 1 ----------------
    CONV(32,0,32,0, TB2, nullptr, nbri2, W32+6*S32,   bn32+7*64,  nullptr, TU1, N1);
    CONV(32,0,32,0, X1,  nullptr, nbr1,  W32+7*S32,   bn32+8*64,  nullptr, TA,  N1);
    CONV(32,0,32,1, TA,  nullptr, nbr1,  W32+8*S32,   bn32+9*64,  X1,      TA2, N1);
    CONV(32,32,32,2, TU1, TA2,    nbr1,  W6432+2*S6432, bn32+13*64, nullptr, TA,  N1);
    // ---------------- head ----------------
    CONV(32,0,32,0, TA,  nullptr, nbr1,  W32+9*S32,   bn32+10*64, nullptr, OUT, N1);
#undef CONV
}